// Round 6
// baseline (114.606 us; speedup 1.0000x reference)
//
#include <hip/hip_runtime.h>
#include <cstdint>
#include <cstddef>

#define NB 32768      // batch rows
#define KI 512        // input dim
#define NE 8          // experts
#define NX 128        // expert output dim
#define NT 2          // tasks
#define NWD 64        // tower hidden width
#define BM 128        // rows per block
#define THREADS 512
#define SMEM_BYTES 163840
#define WOFF   131072    // W quad-buffer LDS offset
#define CHUNK_B 8192     // one W chunk: 256 cols x 16 k x 2B

// workspace layout (ushort elements)
#define W2_ELEMS (NE * KI * NX)          // 524288 bf16 (1 MiB)
#define G2_OFF   W2_ELEMS
#define G2_ELEMS (64 * 16 * 8)           // 16 KiB
#define T2_OFF   (G2_OFF + G2_ELEMS)
#define T2_ELEMS (NT * 16 * 64 * 8)      // 32 KiB
#define WS_NEED  ((size_t)(W2_ELEMS + G2_ELEMS + T2_ELEMS) * 2)

typedef __attribute__((ext_vector_type(8))) short bf16x8;
typedef __attribute__((ext_vector_type(4))) float f32x4;
typedef __attribute__((ext_vector_type(16))) float f32x16;
typedef __attribute__((ext_vector_type(16))) unsigned int u32x16;

#define ZERO16 (f32x16){0.f,0.f,0.f,0.f,0.f,0.f,0.f,0.f,0.f,0.f,0.f,0.f,0.f,0.f,0.f,0.f}
#define ZEROU16 (u32x16){0,0,0,0,0,0,0,0,0,0,0,0,0,0,0,0}

__device__ __forceinline__ unsigned short f2bf(float f) {
  union { float f; unsigned u; } v; v.f = f;
  return (unsigned short)((v.u + 0x7fffu + ((v.u >> 16) & 1u)) >> 16);
}
__device__ __forceinline__ float bf2f(unsigned short u) {
  union { unsigned u; float f; } v; v.u = ((unsigned)u) << 16;
  return v.f;
}

#define AS1(p) ((const __attribute__((address_space(1))) void*)(uintptr_t)(p))
#define AS3(p) ((__attribute__((address_space(3))) void*)(uintptr_t)(p))
#define VMCNT2() asm volatile("s_waitcnt vmcnt(2)" ::: "memory")
#define BAR()    __builtin_amdgcn_s_barrier()

// Repack We f32 [E][I][X] -> bf16 chunk-frag order.
// Chunk cc = n*32+kc (n=expert pair, kc=K/16). Within chunk: [kb(2)][col(256)][8 bf16]
// frag value[j] = We[2n + (col>>7)][kc*16 + kb*8 + j][col&127]
__global__ __launch_bounds__(256) void repack_we_kernel(const float* __restrict__ We,
                                                        unsigned short* __restrict__ ws) {
  int F = blockIdx.x * 256 + threadIdx.x;  // 65536 frags
  int col = F & 255;
  int kb  = (F >> 8) & 1;
  int kc  = (F >> 9) & 31;
  int n   = F >> 14;
  int e   = 2 * n + (col >> 7);
  const float* src = We + ((size_t)e * KI + (size_t)(kc * 16 + kb * 8)) * NX + (col & 127);
  bf16x8 v;
#pragma unroll
  for (int j = 0; j < 8; ++j) v[j] = (short)f2bf(src[(size_t)j * NX]);
  *(bf16x8*)(ws + (size_t)F * 8) = v;
}

// Repack gates [T][I][E] and tW1 [T][X][W] into 16x16x32 fragment order.
__global__ __launch_bounds__(256) void repack_aux_kernel(const float* __restrict__ gates,
                                                         const float* __restrict__ tW1,
                                                         unsigned short* __restrict__ ws) {
  int tid = threadIdx.x;
#pragma unroll
  for (int i = 0; i < 4; ++i) {
    int f = i * 256 + tid;             // 1024 frags: kb*16 + (t*8+e)
    int kb = f >> 4, col = f & 15;
    int t = col >> 3, e = col & 7;
    const float* src = gates + (size_t)t * (KI * NE) + (size_t)(kb * 8) * NE + e;
    bf16x8 v;
#pragma unroll
    for (int j = 0; j < 8; ++j) v[j] = (short)f2bf(src[(size_t)j * NE]);
    *(bf16x8*)(ws + G2_OFF + (size_t)f * 8) = v;
  }
#pragma unroll
  for (int i = 0; i < 8; ++i) {
    int f = i * 256 + tid;             // 2048 frags: (t*16+kb)*64 + col
    int t = f >> 10, kb = (f >> 6) & 15, col = f & 63;
    const float* src = tW1 + (size_t)t * (NX * NWD) + (size_t)(kb * 8) * NWD + col;
    bf16x8 v;
#pragma unroll
    for (int j = 0; j < 8; ++j) v[j] = (short)f2bf(src[(size_t)j * NWD]);
    *(bf16x8*)(ws + T2_OFF + (size_t)f * 8) = v;
  }
}

template <bool USE_WS>
__global__ __launch_bounds__(THREADS, 1)
void moe_fused_kernel(const float* __restrict__ x, const float* __restrict__ We,
                      const float* __restrict__ be, const float* __restrict__ gates,
                      const float* __restrict__ tW1, const float* __restrict__ tb1,
                      const float* __restrict__ tW2, const float* __restrict__ tb2,
                      const unsigned short* __restrict__ ws, float* __restrict__ out) {
  extern __shared__ char smem[];
  // [0,131072)  x tile [128 rows][512 k] bf16, row stride 1024B, 16B-XOR swizzle/row.
  // [131072,163840) W quad buffer: 4 x 8KB chunks, [kb(2)][col(256)][16B] linear.
  // After expert loop, [0,65536) reused: shared tile [t][128 rows][128 cols] bf16.
  char* wbuf = smem + WOFF;

  const int tid  = threadIdx.x;
  const int lane = tid & 63;
  const int wid  = tid >> 6;     // 8 waves: 2 row-groups x 4 col-groups
  const int l15  = lane & 15;
  const int lhi  = lane >> 4;
  const int l31  = lane & 31;
  const int h    = lane >> 5;    // 0/1
  const int wr   = wid >> 2;     // 0..1 : rows wr*64..+63
  const int wc   = wid & 3;      // 0..3
  const int row0 = blockIdx.x * BM;

  // ---------- stage x upfront (coalesced), one barrier ----------
  {
    const float4* xs4 = (const float4*)(x + (size_t)row0 * KI);
#pragma unroll
    for (int c = 0; c < 16; ++c) {
      int i = c * THREADS + tid;             // 8192 groups of 8 floats
      float4 a0 = xs4[(size_t)i * 2];
      float4 a1 = xs4[(size_t)i * 2 + 1];
      bf16x8 v;
      v[0] = (short)f2bf(a0.x); v[1] = (short)f2bf(a0.y);
      v[2] = (short)f2bf(a0.z); v[3] = (short)f2bf(a0.w);
      v[4] = (short)f2bf(a1.x); v[5] = (short)f2bf(a1.y);
      v[6] = (short)f2bf(a1.z); v[7] = (short)f2bf(a1.w);
      int row = i >> 6;
      int kb  = (i & 63) * 16;
      *(bf16x8*)(smem + row * 1024 + (kb ^ ((row & 7) << 4))) = v;
    }
  }
  __syncthreads();

  // ---------- W chunk staging ----------
  auto stage_w = [&](int cc) {   // cc in [0,128)
    if constexpr (USE_WS) {
      const char* gb = (const char*)ws + (size_t)cc * CHUNK_B;
      char* lb = wbuf + (cc & 3) * CHUNK_B + wid * 1024;
      __builtin_amdgcn_global_load_lds(AS1(gb + (wid * 64 + lane) * 16), AS3(lb), 16, 0, 0);
    } else {
      const int n = cc >> 5, kc = cc & 31;
      const int col = tid & 255, kb = tid >> 8;
      const int e = 2 * n + (col >> 7);
      const float* src = We + ((size_t)e * KI + (size_t)(kc * 16 + kb * 8)) * NX + (col & 127);
      bf16x8 v;
#pragma unroll
      for (int j = 0; j < 8; ++j) v[j] = (short)f2bf(src[(size_t)j * NX]);
      *(bf16x8*)(wbuf + (cc & 3) * CHUNK_B + tid * 16) = v;
    }
  };

  stage_w(0);
  stage_w(1);

  const int asw = (lane & 7) << 4;

  // ---------- g prologue: 16x16x32 MFMAs over wave's 64 rows ----------
  f32x4 g16[4] = {{0.f,0.f,0.f,0.f},{0.f,0.f,0.f,0.f},{0.f,0.f,0.f,0.f},{0.f,0.f,0.f,0.f}};
  {
    const char* abg = smem + (wr * 64 + l15) * 1024;   // + rfg*16*1024
#pragma unroll
    for (int gks = 0; gks < 16; ++gks) {
      bf16x8 gb;
      if constexpr (USE_WS) {
        gb = *(const bf16x8*)(ws + G2_OFF + ((size_t)(gks * 4 + lhi) * 16 + l15) * 8);
      } else {
        int t = l15 >> 3, e = l15 & 7;
        const float* src = gates + (size_t)t * (KI * NE) + (size_t)((gks * 4 + lhi) * 8) * NE + e;
#pragma unroll
        for (int j = 0; j < 8; ++j) gb[j] = (short)f2bf(src[(size_t)j * NE]);
      }
      const int ao = (gks * 64 + lhi * 16) ^ asw;
#pragma unroll
      for (int rfg = 0; rfg < 4; ++rfg)
        g16[rfg] = __builtin_amdgcn_mfma_f32_16x16x32_bf16(
            *(const bf16x8*)(abg + rfg * 16384 + ao), gb, g16[rfg], 0, 0, 0);
    }
  }

  // preload be for this wave's 4 experts x 2 col-frags
  float be_r[4][2];
#pragma unroll
  for (int n = 0; n < 4; ++n)
#pragma unroll
    for (int cf = 0; cf < 2; ++cf)
      be_r[n][cf] = be[(2 * n + (wc >> 1)) * NX + (wc & 1) * 64 + cf * 32 + l31];

  // ---------- shared accumulators: 2 tasks packed as bf16 lo(t0)/hi(t1) ----------
  u32x16 shpk[2][2];
  shpk[0][0] = ZEROU16; shpk[0][1] = ZEROU16; shpk[1][0] = ZEROU16; shpk[1][1] = ZEROU16;

  const char* abase0 = smem + (wr * 64 + l31) * 1024;
  const char* abase1 = abase0 + 32 * 1024;
  const int boff0 = (h * 256 + wc * 64 + l31) * 16;

  // ---------- main loop: 4 N-tiles (expert pairs) x 32 K-chunks ----------
#pragma unroll
  for (int n = 0; n < 4; ++n) {
    f32x16 acc[2][2];
    acc[0][0] = ZERO16; acc[0][1] = ZERO16; acc[1][0] = ZERO16; acc[1][1] = ZERO16;
#pragma unroll 4
    for (int kc = 0; kc < 32; ++kc) {
      const int c = n * 32 + kc;
      stage_w((c + 2) & 127);
      if constexpr (USE_WS) { VMCNT2(); BAR(); } else { __syncthreads(); }
      const char* bb = wbuf + (c & 3) * CHUNK_B;
      const int ao = (kc * 32 + h * 16) ^ asw;   // K offset within row (kc only)
      bf16x8 a0 = *(const bf16x8*)(abase0 + ao);
      bf16x8 a1 = *(const bf16x8*)(abase1 + ao);
      bf16x8 b0 = *(const bf16x8*)(bb + boff0);
      bf16x8 b1 = *(const bf16x8*)(bb + boff0 + 512);
      acc[0][0] = __builtin_amdgcn_mfma_f32_32x32x16_bf16(a0, b0, acc[0][0], 0, 0, 0);
      acc[0][1] = __builtin_amdgcn_mfma_f32_32x32x16_bf16(a0, b1, acc[0][1], 0, 0, 0);
      acc[1][0] = __builtin_amdgcn_mfma_f32_32x32x16_bf16(a1, b0, acc[1][0], 0, 0, 0);
      acc[1][1] = __builtin_amdgcn_mfma_f32_32x32x16_bf16(a1, b1, acc[1][1], 0, 0, 0);
    }
    // ---------- epilogue: relu(+be), shared(bf16-packed) += g*ex ----------
    {
      const int ew = __builtin_amdgcn_readfirstlane(2 * n + (wc >> 1));
#pragma unroll
      for (int rf = 0; rf < 2; ++rf)
#pragma unroll
        for (int reg = 0; reg < 16; ++reg) {
          const int f  = rf * 2 + (reg >> 3);
          const int r  = reg & 3;
          const int b0i = 32 * ((reg >> 2) & 1);
          int vi = __float_as_int(g16[f][r]);
          float g00 = __int_as_float(__builtin_amdgcn_readlane(vi, ew + b0i));       // t0,h0
          float g01 = __int_as_float(__builtin_amdgcn_readlane(vi, ew + b0i + 16));  // t0,h1
          float g10 = __int_as_float(__builtin_amdgcn_readlane(vi, ew + b0i + 8));   // t1,h0
          float g11 = __int_as_float(__builtin_amdgcn_readlane(vi, ew + b0i + 24));  // t1,h1
          float gv0 = h ? g01 : g00;
          float gv1 = h ? g11 : g10;
          float ex0 = fmaxf(acc[rf][0][reg] + be_r[n][0], 0.f);
          float ex1 = fmaxf(acc[rf][1][reg] + be_r[n][1], 0.f);
          unsigned p0 = shpk[rf][0][reg];
          float s00 = bf2f((unsigned short)(p0 & 0xffffu)) + gv0 * ex0;
          float s01 = bf2f((unsigned short)(p0 >> 16))     + gv1 * ex0;
          shpk[rf][0][reg] = ((unsigned)f2bf(s01) << 16) | (unsigned)f2bf(s00);
          unsigned p1 = shpk[rf][1][reg];
          float s10 = bf2f((unsigned short)(p1 & 0xffffu)) + gv0 * ex1;
          float s11 = bf2f((unsigned short)(p1 >> 16))     + gv1 * ex1;
          shpk[rf][1][reg] = ((unsigned)f2bf(s11) << 16) | (unsigned)f2bf(s10);
        }
    }
  }

  // ---------- combine partner partials into bf16 shared tile ----------
  __syncthreads();   // all waves done reading x region
  auto sh_io = [&](bool combine) {
#pragma unroll
    for (int t = 0; t < NT; ++t)
#pragma unroll
      for (int rf = 0; rf < 2; ++rf)
#pragma unroll
        for (int cf = 0; cf < 2; ++cf)
#pragma unroll
          for (int reg = 0; reg < 16; ++reg) {
            int row = wr * 64 + rf * 32 + (reg & 3) + 8 * (reg >> 2) + 4 * h;
            int col = (wc & 1) * 64 + cf * 32 + l31;
            char* p = smem + t * 32768 + row * 256 + ((col * 2) ^ ((row & 7) << 4));
            unsigned pk = shpk[rf][cf][reg];
            float v = bf2f((unsigned short)(t ? (pk >> 16) : (pk & 0xffffu)));
            if (combine) v += bf2f(*(unsigned short*)p);
            *(unsigned short*)p = f2bf(v);
          }
  };
  if (wc < 2) sh_io(false);
  __syncthreads();
  if (wc >= 2) sh_io(true);
  __syncthreads();

  // ---------- tower ----------
  const int trow = wid * 16 + l15;
  const char* tbase = smem + trow * 256;
  const int tsw = (trow & 7) << 4;
#pragma unroll
  for (int t = 0; t < NT; ++t) {
    f32x4 hacc[4];
#pragma unroll
    for (int cf = 0; cf < 4; ++cf) hacc[cf] = (f32x4){0.f, 0.f, 0.f, 0.f};
#pragma unroll
    for (int ks = 0; ks < 4; ++ks) {
      bf16x8 a = *(const bf16x8*)(tbase + t * 32768 + ((ks * 64 + lhi * 16) ^ tsw));
#pragma unroll
      for (int cf = 0; cf < 4; ++cf) {
        bf16x8 bv;
        if constexpr (USE_WS) {
          bv = *(const bf16x8*)(ws + T2_OFF + ((size_t)(t * 16 + ks * 4 + lhi) * 64 + cf * 16 + l15) * 8);
        } else {
          const float* src = tW1 + (size_t)t * (NX * NWD) + (size_t)((ks * 4 + lhi) * 8) * NWD + cf * 16 + l15;
#pragma unroll
          for (int j = 0; j < 8; ++j) bv[j] = (short)f2bf(src[(size_t)j * NWD]);
        }
        hacc[cf] = __builtin_amdgcn_mfma_f32_16x16x32_bf16(a, bv, hacc[cf], 0, 0, 0);
      }
    }
    float p[4] = {0.f, 0.f, 0.f, 0.f};
#pragma unroll
    for (int cf = 0; cf < 4; ++cf) {
      int col = cf * 16 + l15;
      const float b1v = tb1[t * NWD + col];
      const float w2v = tW2[t * NWD + col];
#pragma unroll
      for (int r = 0; r < 4; ++r) p[r] += fmaxf(hacc[cf][r] + b1v, 0.f) * w2v;
    }
#pragma unroll
    for (int r = 0; r < 4; ++r) {
      p[r] += __shfl_xor(p[r], 1, 64);
      p[r] += __shfl_xor(p[r], 2, 64);
      p[r] += __shfl_xor(p[r], 4, 64);
      p[r] += __shfl_xor(p[r], 8, 64);
    }
    if (l15 == 0) {
      const float b2 = tb2[t];
      float4 o;
      o.x = p[0] + b2; o.y = p[1] + b2; o.z = p[2] + b2; o.w = p[3] + b2;
      *(float4*)(out + (size_t)t * NB + row0 + wid * 16 + lhi * 4) = o;
    }
  }
}

extern "C" void kernel_launch(void* const* d_in, const int* in_sizes, int n_in,
                              void* d_out, int out_size, void* d_ws, size_t ws_size,
                              hipStream_t stream) {
  const float* x     = (const float*)d_in[0];
  const float* We    = (const float*)d_in[1];
  const float* be    = (const float*)d_in[2];
  const float* gates = (const float*)d_in[3];
  const float* tW1   = (const float*)d_in[4];
  const float* tb1   = (const float*)d_in[5];
  const float* tW2   = (const float*)d_in[6];
  const float* tb2   = (const float*)d_in[7];
  float* out = (float*)d_out;

  const bool use_ws = (d_ws != nullptr) && (ws_size >= WS_NEED);
  const int nblk = NB / BM;  // 256

  if (use_ws) {
    unsigned short* ws = (unsigned short*)d_ws;
    hipFuncSetAttribute(reinterpret_cast<const void*>(moe_fused_kernel<true>),
                        hipFuncAttributeMaxDynamicSharedMemorySize, SMEM_BYTES);
    repack_we_kernel<<<(W2_ELEMS / 8) / 256, 256, 0, stream>>>(We, ws);
    repack_aux_kernel<<<1, 256, 0, stream>>>(gates, tW1, ws);
    moe_fused_kernel<true><<<nblk, THREADS, SMEM_BYTES, stream>>>(
        x, We, be, gates, tW1, tb1, tW2, tb2, ws, out);
  } else {
    hipFuncSetAttribute(reinterpret_cast<const void*>(moe_fused_kernel<false>),
                        hipFuncAttributeMaxDynamicSharedMemorySize, SMEM_BYTES);
    moe_fused_kernel<false><<<nblk, THREADS, SMEM_BYTES, stream>>>(
        x, We, be, gates, tW1, tb1, tW2, tb2, nullptr, out);
  }
}

// Round 7
// 82.203 us; speedup vs baseline: 1.3942x; 1.3942x over previous
//
#include <hip/hip_runtime.h>
#include <cstdint>
#include <cstddef>

#define NB 32768      // batch rows
#define KI 512        // input dim
#define NE 8          // experts
#define NX 128        // expert output dim
#define NT 2          // tasks
#define NWD 64        // tower hidden width
#define BM 128        // rows per block
#define THREADS 512
#define SMEM_BYTES 163840
#define WOFF   131072    // W quad-buffer LDS offset
#define CHUNK_B 8192     // one W chunk: 128 cols x 32 k x 2B

// workspace layout (ushort elements)
#define W2_ELEMS (NE * KI * NX)          // 524288 bf16 (1 MiB)
#define G2_OFF   W2_ELEMS
#define G2_ELEMS (64 * 16 * 8)           // 16 KiB
#define T2_OFF   (G2_OFF + G2_ELEMS)
#define T2_ELEMS (NT * 16 * 64 * 8)      // 32 KiB
#define WS_NEED  ((size_t)(W2_ELEMS + G2_ELEMS + T2_ELEMS) * 2)

typedef __attribute__((ext_vector_type(8))) short bf16x8;
typedef __attribute__((ext_vector_type(4))) float f32x4;
typedef __attribute__((ext_vector_type(16))) float f32x16;
typedef __attribute__((ext_vector_type(16))) unsigned int u32x16;

#define ZERO16 (f32x16){0.f,0.f,0.f,0.f,0.f,0.f,0.f,0.f,0.f,0.f,0.f,0.f,0.f,0.f,0.f,0.f}
#define ZEROU16 (u32x16){0,0,0,0,0,0,0,0,0,0,0,0,0,0,0,0}

__device__ __forceinline__ unsigned short f2bf(float f) {
  union { float f; unsigned u; } v; v.f = f;
  return (unsigned short)((v.u + 0x7fffu + ((v.u >> 16) & 1u)) >> 16);
}
__device__ __forceinline__ float bf2f(unsigned short u) {
  union { unsigned u; float f; } v; v.u = ((unsigned)u) << 16;
  return v.f;
}

#define AS1(p) ((const __attribute__((address_space(1))) void*)(uintptr_t)(p))
#define AS3(p) ((__attribute__((address_space(3))) void*)(uintptr_t)(p))
#define VMCNT2() asm volatile("s_waitcnt vmcnt(2)" ::: "memory")
#define BAR()    __builtin_amdgcn_s_barrier()

// Repack We f32 [E][I][X] -> bf16 fragment order: frag(e,kblk,col)[j] = We[e][kblk*8+j][col]
// Chunk cc = e*16+kc covers kblk [kc*4, kc*4+4) contiguous (8 KB).
__global__ __launch_bounds__(256) void repack_we_kernel(const float* __restrict__ We,
                                                        unsigned short* __restrict__ ws) {
  int F = blockIdx.x * 256 + threadIdx.x;  // 65536 frags
  int col  = F & (NX - 1);
  int kblk = (F >> 7) & 63;
  int e    = F >> 13;
  const float* src = We + ((size_t)e * KI + (size_t)kblk * 8) * NX + col;
  bf16x8 v;
#pragma unroll
  for (int j = 0; j < 8; ++j) v[j] = (short)f2bf(src[(size_t)j * NX]);
  *(bf16x8*)(ws + (size_t)F * 8) = v;
}

// Repack gates [T][I][E] and tW1 [T][X][W] into 16x16x32 fragment order.
__global__ __launch_bounds__(256) void repack_aux_kernel(const float* __restrict__ gates,
                                                         const float* __restrict__ tW1,
                                                         unsigned short* __restrict__ ws) {
  int tid = threadIdx.x;
#pragma unroll
  for (int i = 0; i < 4; ++i) {
    int f = i * 256 + tid;             // 1024 frags: kb*16 + (t*8+e)
    int kb = f >> 4, col = f & 15;
    int t = col >> 3, e = col & 7;
    const float* src = gates + (size_t)t * (KI * NE) + (size_t)(kb * 8) * NE + e;
    bf16x8 v;
#pragma unroll
    for (int j = 0; j < 8; ++j) v[j] = (short)f2bf(src[(size_t)j * NE]);
    *(bf16x8*)(ws + G2_OFF + (size_t)f * 8) = v;
  }
#pragma unroll
  for (int i = 0; i < 8; ++i) {
    int f = i * 256 + tid;             // 2048 frags: (t*16+kb)*64 + col
    int t = f >> 10, kb = (f >> 6) & 15, col = f & 63;
    const float* src = tW1 + (size_t)t * (NX * NWD) + (size_t)(kb * 8) * NWD + col;
    bf16x8 v;
#pragma unroll
    for (int j = 0; j < 8; ++j) v[j] = (short)f2bf(src[(size_t)j * NWD]);
    *(bf16x8*)(ws + T2_OFF + (size_t)f * 8) = v;
  }
}

template <bool USE_WS>
__global__ __launch_bounds__(THREADS, 2)
void moe_fused_kernel(const float* __restrict__ x, const float* __restrict__ We,
                      const float* __restrict__ be, const float* __restrict__ gates,
                      const float* __restrict__ tW1, const float* __restrict__ tb1,
                      const float* __restrict__ tW2, const float* __restrict__ tb2,
                      const unsigned short* __restrict__ ws, float* __restrict__ out) {
  extern __shared__ char smem[];
  // [0,131072)  x tile [128 rows][512 k] bf16, row stride 1024B, 16B-XOR swizzle/row.
  // [131072,163840) W quad buffer: 4 x 8KB chunks, [kbb(4)][col(128)][16B] linear.
  // After expert loop, [0,65536) reused: shared tile [t][128 rows][128 cols] bf16.
  char* wbuf = smem + WOFF;

  const int tid  = threadIdx.x;
  const int lane = tid & 63;
  const int wid  = tid >> 6;     // 8 waves: 4 row-groups x 2 col-groups
  const int l15  = lane & 15;
  const int lhi  = lane >> 4;
  const int l31  = lane & 31;
  const int h    = lane >> 5;    // 0/1
  const int wr   = wid >> 1;     // 0..3 : rows wr*32..+31
  const int wc   = wid & 1;      // 0..1 : X-cols wc*64..+63
  const int row0 = blockIdx.x * BM;

  // ---------- stage x upfront (coalesced), one barrier ----------
  {
    const float4* xs4 = (const float4*)(x + (size_t)row0 * KI);
#pragma unroll
    for (int c = 0; c < 16; ++c) {
      int i = c * THREADS + tid;             // 8192 groups of 8 floats
      float4 a0 = xs4[(size_t)i * 2];
      float4 a1 = xs4[(size_t)i * 2 + 1];
      bf16x8 v;
      v[0] = (short)f2bf(a0.x); v[1] = (short)f2bf(a0.y);
      v[2] = (short)f2bf(a0.z); v[3] = (short)f2bf(a0.w);
      v[4] = (short)f2bf(a1.x); v[5] = (short)f2bf(a1.y);
      v[6] = (short)f2bf(a1.z); v[7] = (short)f2bf(a1.w);
      int row = i >> 6;
      int kb  = (i & 63) * 16;
      *(bf16x8*)(smem + row * 1024 + (kb ^ ((row & 7) << 4))) = v;
    }
  }
  __syncthreads();

  // ---------- W chunk staging (1 global_load_lds / thread / chunk) ----------
  auto stage_w = [&](int cc) {   // cc in [0,128): e*16+kc
    if constexpr (USE_WS) {
      const char* gb = (const char*)ws + (size_t)cc * CHUNK_B;
      char* lb = wbuf + (cc & 3) * CHUNK_B + wid * 1024;
      __builtin_amdgcn_global_load_lds(AS1(gb + (wid * 64 + lane) * 16), AS3(lb), 16, 0, 0);
    } else {
      const int e = cc >> 4, kc = cc & 15;
      const int col = tid & 127, kbb = tid >> 7;   // kbb 0..3
      const float* src = We + ((size_t)e * KI + (size_t)(kc * 32 + kbb * 8)) * NX + col;
      bf16x8 v;
#pragma unroll
      for (int j = 0; j < 8; ++j) v[j] = (short)f2bf(src[(size_t)j * NX]);
      *(bf16x8*)(wbuf + (cc & 3) * CHUNK_B + tid * 16) = v;
    }
  };

  stage_w(0);
  stage_w(1);

  // ---------- g prologue: 16x16x32 MFMAs over wave's 32 rows ----------
  f32x4 g16[2] = {{0.f,0.f,0.f,0.f},{0.f,0.f,0.f,0.f}};
  {
    const char* abg = smem + (wr * 32 + l15) * 1024;   // + rfg*16*1024
    const int gsw = (l15 & 7) << 4;
#pragma unroll
    for (int gks = 0; gks < 16; ++gks) {
      bf16x8 gb;
      if constexpr (USE_WS) {
        gb = *(const bf16x8*)(ws + G2_OFF + ((size_t)(gks * 4 + lhi) * 16 + l15) * 8);
      } else {
        int t = l15 >> 3, e = l15 & 7;
        const float* src = gates + (size_t)t * (KI * NE) + (size_t)((gks * 4 + lhi) * 8) * NE + e;
#pragma unroll
        for (int j = 0; j < 8; ++j) gb[j] = (short)f2bf(src[(size_t)j * NE]);
      }
      const int ao = (gks * 64 + lhi * 16) ^ gsw;
      g16[0] = __builtin_amdgcn_mfma_f32_16x16x32_bf16(*(const bf16x8*)(abg + ao), gb, g16[0], 0, 0, 0);
      g16[1] = __builtin_amdgcn_mfma_f32_16x16x32_bf16(*(const bf16x8*)(abg + 16384 + ao), gb, g16[1], 0, 0, 0);
    }
  }

  // preload be for all 8 experts x 2 col-frags (static-indexed after unroll)
  float be_r[NE][2];
#pragma unroll
  for (int e = 0; e < NE; ++e)
#pragma unroll
    for (int cf = 0; cf < 2; ++cf)
      be_r[e][cf] = be[e * NX + wc * 64 + cf * 32 + l31];

  // ---------- shared accumulators: 2 tasks packed bf16 lo(t0)/hi(t1), dup=1 ----------
  u32x16 shpk[2];
  shpk[0] = ZEROU16; shpk[1] = ZEROU16;

  const char* abase = smem + (wr * 32 + l31) * 1024;
  const int asw = (l31 & 7) << 4;
  const int bcol16 = (wc * 64 + l31) * 16;   // + cf*512, + (ks*2+h)*2048

  // ---------- main loop: 8 experts x 16 K-chunks (K=32 each) ----------
#pragma unroll
  for (int e = 0; e < NE; ++e) {
    f32x16 acc0 = ZERO16, acc1 = ZERO16;
#pragma unroll 4
    for (int kc = 0; kc < 16; ++kc) {
      const int cc = e * 16 + kc;
      stage_w((cc + 2) & 127);
      if constexpr (USE_WS) { VMCNT2(); BAR(); } else { __syncthreads(); }
      const char* bb = wbuf + (cc & 3) * CHUNK_B;
#pragma unroll
      for (int ks = 0; ks < 2; ++ks) {
        bf16x8 a  = *(const bf16x8*)(abase + ((kc * 64 + ks * 32 + h * 16) ^ asw));
        bf16x8 b0 = *(const bf16x8*)(bb + (ks * 2 + h) * 2048 + bcol16);
        bf16x8 b1 = *(const bf16x8*)(bb + (ks * 2 + h) * 2048 + bcol16 + 512);
        acc0 = __builtin_amdgcn_mfma_f32_32x32x16_bf16(a, b0, acc0, 0, 0, 0);
        acc1 = __builtin_amdgcn_mfma_f32_32x32x16_bf16(a, b1, acc1, 0, 0, 0);
      }
      if constexpr (USE_WS) { BAR(); } else { __syncthreads(); }
    }
    // ---------- epilogue: relu(+be), shared(bf16-packed) += g*ex ----------
#pragma unroll
    for (int reg = 0; reg < 16; ++reg) {
      const int b0i = 32 * ((reg >> 2) & 1);
      const int vi = __float_as_int(g16[reg >> 3][reg & 3]);
      const float g00 = __int_as_float(__builtin_amdgcn_readlane(vi, b0i + e));        // t0,h0
      const float g01 = __int_as_float(__builtin_amdgcn_readlane(vi, b0i + 16 + e));   // t0,h1
      const float g10 = __int_as_float(__builtin_amdgcn_readlane(vi, b0i + 8 + e));    // t1,h0
      const float g11 = __int_as_float(__builtin_amdgcn_readlane(vi, b0i + 24 + e));   // t1,h1
      const float gv0 = h ? g01 : g00;
      const float gv1 = h ? g11 : g10;
      const float ex0 = fmaxf(acc0[reg] + be_r[e][0], 0.f);
      const float ex1 = fmaxf(acc1[reg] + be_r[e][1], 0.f);
      unsigned p0 = shpk[0][reg];
      float s00 = bf2f((unsigned short)(p0 & 0xffffu)) + gv0 * ex0;
      float s01 = bf2f((unsigned short)(p0 >> 16))     + gv1 * ex0;
      shpk[0][reg] = ((unsigned)f2bf(s01) << 16) | (unsigned)f2bf(s00);
      unsigned p1 = shpk[1][reg];
      float s10 = bf2f((unsigned short)(p1 & 0xffffu)) + gv0 * ex1;
      float s11 = bf2f((unsigned short)(p1 >> 16))     + gv1 * ex1;
      shpk[1][reg] = ((unsigned)f2bf(s11) << 16) | (unsigned)f2bf(s10);
    }
  }

  // ---------- write shared tile (dup=1: single race-free pass) ----------
  __syncthreads();   // all waves done reading x region
#pragma unroll
  for (int cf = 0; cf < 2; ++cf)
#pragma unroll
    for (int reg = 0; reg < 16; ++reg) {
      const int row = wr * 32 + (reg & 3) + 8 * (reg >> 2) + 4 * h;
      const int col = wc * 64 + cf * 32 + l31;
      const unsigned pk = shpk[cf][reg];
      char* p = smem + row * 256 + ((col * 2) ^ ((row & 7) << 4));
      *(unsigned short*)p = (unsigned short)(pk & 0xffffu);            // task 0
      *(unsigned short*)(p + 32768) = (unsigned short)(pk >> 16);      // task 1
    }
  __syncthreads();

  // ---------- tower ----------
  const int trow = wid * 16 + l15;
  const char* tbase = smem + trow * 256;
  const int tsw = (trow & 7) << 4;
#pragma unroll
  for (int t = 0; t < NT; ++t) {
    f32x4 hacc[4];
#pragma unroll
    for (int cf = 0; cf < 4; ++cf) hacc[cf] = (f32x4){0.f, 0.f, 0.f, 0.f};
#pragma unroll
    for (int ks = 0; ks < 4; ++ks) {
      bf16x8 a = *(const bf16x8*)(tbase + t * 32768 + ((ks * 64 + lhi * 16) ^ tsw));
#pragma unroll
      for (int cf = 0; cf < 4; ++cf) {
        bf16x8 bv;
        if constexpr (USE_WS) {
          bv = *(const bf16x8*)(ws + T2_OFF + ((size_t)(t * 16 + ks * 4 + lhi) * 64 + cf * 16 + l15) * 8);
        } else {
          const float* src = tW1 + (size_t)t * (NX * NWD) + (size_t)((ks * 4 + lhi) * 8) * NWD + cf * 16 + l15;
#pragma unroll
          for (int j = 0; j < 8; ++j) bv[j] = (short)f2bf(src[(size_t)j * NWD]);
        }
        hacc[cf] = __builtin_amdgcn_mfma_f32_16x16x32_bf16(a, bv, hacc[cf], 0, 0, 0);
      }
    }
    float p[4] = {0.f, 0.f, 0.f, 0.f};
#pragma unroll
    for (int cf = 0; cf < 4; ++cf) {
      int col = cf * 16 + l15;
      const float b1v = tb1[t * NWD + col];
      const float w2v = tW2[t * NWD + col];
#pragma unroll
      for (int r = 0; r < 4; ++r) p[r] += fmaxf(hacc[cf][r] + b1v, 0.f) * w2v;
    }
#pragma unroll
    for (int r = 0; r < 4; ++r) {
      p[r] += __shfl_xor(p[r], 1, 64);
      p[r] += __shfl_xor(p[r], 2, 64);
      p[r] += __shfl_xor(p[r], 4, 64);
      p[r] += __shfl_xor(p[r], 8, 64);
    }
    if (l15 == 0) {
      const float b2 = tb2[t];
      float4 o;
      o.x = p[0] + b2; o.y = p[1] + b2; o.z = p[2] + b2; o.w = p[3] + b2;
      *(float4*)(out + (size_t)t * NB + row0 + wid * 16 + lhi * 4) = o;
    }
  }
}

extern "C" void kernel_launch(void* const* d_in, const int* in_sizes, int n_in,
                              void* d_out, int out_size, void* d_ws, size_t ws_size,
                              hipStream_t stream) {
  const float* x     = (const float*)d_in[0];
  const float* We    = (const float*)d_in[1];
  const float* be    = (const float*)d_in[2];
  const float* gates = (const float*)d_in[3];
  const float* tW1   = (const float*)d_in[4];
  const float* tb1   = (const float*)d_in[5];
  const float* tW2   = (const float*)d_in[6];
  const float* tb2   = (const float*)d_in[7];
  float* out = (float*)d_out;

  const bool use_ws = (d_ws != nullptr) && (ws_size >= WS_NEED);
  const int nblk = NB / BM;  // 256

  if (use_ws) {
    unsigned short* ws = (unsigned short*)d_ws;
    hipFuncSetAttribute(reinterpret_cast<const void*>(moe_fused_kernel<true>),
                        hipFuncAttributeMaxDynamicSharedMemorySize, SMEM_BYTES);
    repack_we_kernel<<<(W2_ELEMS / 8) / 256, 256, 0, stream>>>(We, ws);
    repack_aux_kernel<<<1, 256, 0, stream>>>(gates, tW1, ws);
    moe_fused_kernel<true><<<nblk, THREADS, SMEM_BYTES, stream>>>(
        x, We, be, gates, tW1, tb1, tW2, tb2, ws, out);
  } else {
    hipFuncSetAttribute(reinterpret_cast<const void*>(moe_fused_kernel<false>),
                        hipFuncAttributeMaxDynamicSharedMemorySize, SMEM_BYTES);
    moe_fused_kernel<false><<<nblk, THREADS, SMEM_BYTES, stream>>>(
        x, We, be, gates, tW1, tb1, tW2, tb2, nullptr, out);
  }
}